// Round 1
// baseline (43.592 us; speedup 1.0000x reference)
//
#include <hip/hip_runtime.h>

// SpatialCorrelationSampler(kernel=1, patch=2, stride=2): out[b,0,0,oh,ow] =
// sum_{c,ph,pw} in1[b,c,2oh+ph,2ow+pw] * in2[b,c,2oh+ph,2ow+pw]; other patch
// slots are zero. B=8, C=256, H=W=128, oH=oW=64.

#define B_  8
#define C_  256
#define H_  128
#define W_  128
#define OH_ 64
#define OW_ 64

// 1024 threads = 16 waves/block; __launch_bounds__(1024, 8): 8 waves/EU ->
// 2 blocks/CU -> 32 waves/CU (full occupancy), VGPR capped at 64.
__global__ __launch_bounds__(1024, 8) void
corr_kernel(const float* __restrict__ in1, const float* __restrict__ in2,
            float* __restrict__ out) {
    __shared__ float red[16][64];

    const int bid  = blockIdx.x;       // 0..511
    const int b    = bid >> 6;         // 0..7
    const int oh   = bid & 63;         // 0..63
    const int tid  = threadIdx.x;
    const int wid  = tid >> 6;         // wave 0..15 -> channel group
    const int lane = tid & 63;
    const int r    = lane >> 5;        // row within the 2x2 patch pair: 0/1
    const int q    = lane & 31;        // float4 index within the 128-col row

    // element offset of (b, c=wid, h=2*oh+r, w=4*q)
    size_t base = ((size_t)(b * C_ + wid) * H_ + (2 * oh + r)) * W_ + 4 * q;
    const size_t cstep = (size_t)16 * H_ * W_;   // +16 channels

    float acc0 = 0.f, acc1 = 0.f;                // ow = 2q, 2q+1 partials
    #pragma unroll
    for (int i = 0; i < 16; ++i) {
        const float4 a = *reinterpret_cast<const float4*>(in1 + base + i * cstep);
        const float4 v = *reinterpret_cast<const float4*>(in2 + base + i * cstep);
        acc0 += a.x * v.x + a.y * v.y;
        acc1 += a.z * v.z + a.w * v.w;
    }

    // lanes l and l^32 hold the two patch rows of the same ow pair
    acc0 += __shfl_xor(acc0, 32);
    acc1 += __shfl_xor(acc1, 32);
    if (r == 0) {
        red[wid][2 * q]     = acc0;
        red[wid][2 * q + 1] = acc1;
    }
    __syncthreads();

    if (tid < 64) {
        // sum the 16 per-wave partials for ow = tid
        float s = 0.f;
        #pragma unroll
        for (int wv = 0; wv < 16; ++wv) s += red[wv][tid];
        out[(size_t)(b * 4 + 0) * (OH_ * OW_) + oh * OW_ + tid] = s;
    } else if (tid < 256) {
        // zero patch slots (0,1),(1,0),(1,1) for this (b, oh) row
        const int slot = tid >> 6;     // 1..3
        out[(size_t)(b * 4 + slot) * (OH_ * OW_) + oh * OW_ + (tid & 63)] = 0.f;
    }
}

extern "C" void kernel_launch(void* const* d_in, const int* in_sizes, int n_in,
                              void* d_out, int out_size, void* d_ws, size_t ws_size,
                              hipStream_t stream) {
    const float* in1 = (const float*)d_in[0];
    const float* in2 = (const float*)d_in[1];
    float* out = (float*)d_out;
    dim3 grid(B_ * OH_);   // 512 blocks
    dim3 block(1024);
    corr_kernel<<<grid, block, 0, stream>>>(in1, in2, out);
}